// Round 1
// baseline (79.704 us; speedup 1.0000x reference)
//
#include <hip/hip_runtime.h>

#define NPTS 512
#define DIM 128
#define MARGIN 0.2f

// One block per anchor: compute distance row d[a][*] from z directly,
// then accumulate masked triplet losses for this anchor.
__global__ __launch_bounds__(256) void triplet_partial_kernel(
    const float* __restrict__ z, const int* __restrict__ labels,
    float* __restrict__ psum, unsigned* __restrict__ pcnt,
    unsigned* __restrict__ pntrip)
{
    __shared__ float za[DIM];
    __shared__ float drow[NPTS];
    __shared__ int lab[NPTS];
    __shared__ float red_f[4];
    __shared__ unsigned red_c[4], red_p[4], red_n[4];

    const int a = blockIdx.x;
    const int t = threadIdx.x;

    if (t < DIM) za[t] = z[a * DIM + t];
    lab[t] = labels[t];
    lab[t + 256] = labels[t + 256];
    __syncthreads();

    // Each thread computes distances for columns j = t and j = t + 256.
    #pragma unroll
    for (int jj = 0; jj < 2; ++jj) {
        const int j = t + jj * 256;
        const float4* zr = reinterpret_cast<const float4*>(z + (size_t)j * DIM);
        float acc = 0.f;
        #pragma unroll
        for (int k = 0; k < DIM / 4; ++k) {
            float4 v = zr[k];
            float d0 = za[4 * k + 0] - v.x;
            float d1 = za[4 * k + 1] - v.y;
            float d2 = za[4 * k + 2] - v.z;
            float d3 = za[4 * k + 3] - v.w;
            acc += d0 * d0 + d1 * d1 + d2 * d2 + d3 * d3;
        }
        drow[j] = sqrtf(acc);
    }
    __syncthreads();

    const int la = lab[a];

    // Thread-local negative candidates (n = t and n = t+256).
    const float dn0 = drow[t];
    const float dn1 = drow[t + 256];
    const bool vn0 = (lab[t] != la);
    const bool vn1 = (lab[t + 256] != la);

    // Per-thread contribution to |P_a| and |N_a|.
    unsigned sp = (unsigned)((lab[t] == la) && (t != a))
                + (unsigned)((lab[t + 256] == la) && ((t + 256) != a));
    unsigned sn = (unsigned)vn0 + (unsigned)vn1;

    float sum = 0.f;
    unsigned cnt = 0;
    // p-loop: wave-uniform branch (labels in LDS, broadcast reads).
    for (int p = 0; p < NPTS; ++p) {
        if (lab[p] == la && p != a) {
            const float dpm = drow[p] + MARGIN;
            const float v0 = dpm - dn0;
            const float v1 = dpm - dn1;
            if (vn0 && v0 > 0.f) { sum += v0; ++cnt; }
            if (vn1 && v1 > 0.f) { sum += v1; ++cnt; }
        }
    }

    // Wave (64-lane) reduction.
    #pragma unroll
    for (int off = 32; off > 0; off >>= 1) {
        sum += __shfl_down(sum, off, 64);
        cnt += __shfl_down(cnt, off, 64);
        sp  += __shfl_down(sp,  off, 64);
        sn  += __shfl_down(sn,  off, 64);
    }
    const int wave = t >> 6;
    const int lane = t & 63;
    if (lane == 0) {
        red_f[wave] = sum; red_c[wave] = cnt; red_p[wave] = sp; red_n[wave] = sn;
    }
    __syncthreads();
    if (t == 0) {
        float S = red_f[0] + red_f[1] + red_f[2] + red_f[3];
        unsigned C = red_c[0] + red_c[1] + red_c[2] + red_c[3];
        unsigned P = red_p[0] + red_p[1] + red_p[2] + red_p[3];
        unsigned Nn = red_n[0] + red_n[1] + red_n[2] + red_n[3];
        psum[a] = S;
        pcnt[a] = C;
        pntrip[a] = P * Nn;
    }
}

// Single-block deterministic reduction of the 512 per-anchor partials.
__global__ __launch_bounds__(512) void triplet_final_kernel(
    const float* __restrict__ psum, const unsigned* __restrict__ pcnt,
    const unsigned* __restrict__ pntrip, float* __restrict__ out)
{
    __shared__ float rf[8];
    __shared__ unsigned rc[8], rn[8];

    const int t = threadIdx.x;
    float s = psum[t];
    unsigned c = pcnt[t];
    unsigned nt = pntrip[t];

    #pragma unroll
    for (int off = 32; off > 0; off >>= 1) {
        s  += __shfl_down(s,  off, 64);
        c  += __shfl_down(c,  off, 64);
        nt += __shfl_down(nt, off, 64);
    }
    const int wave = t >> 6;
    const int lane = t & 63;
    if (lane == 0) { rf[wave] = s; rc[wave] = c; rn[wave] = nt; }
    __syncthreads();
    if (t == 0) {
        double S = 0.0;
        unsigned C = 0, NT = 0;
        #pragma unroll
        for (int w = 0; w < 8; ++w) { S += (double)rf[w]; C += rc[w]; NT += rn[w]; }
        out[0] = (float)(S / (double)NT);
        out[1] = (float)C;
    }
}

extern "C" void kernel_launch(void* const* d_in, const int* in_sizes, int n_in,
                              void* d_out, int out_size, void* d_ws, size_t ws_size,
                              hipStream_t stream) {
    const float* z = (const float*)d_in[0];
    const int* labels = (const int*)d_in[1];
    float* out = (float*)d_out;

    float* psum = (float*)d_ws;
    unsigned* pcnt = (unsigned*)((char*)d_ws + NPTS * sizeof(float));
    unsigned* pntrip = pcnt + NPTS;

    triplet_partial_kernel<<<NPTS, 256, 0, stream>>>(z, labels, psum, pcnt, pntrip);
    triplet_final_kernel<<<1, NPTS, 0, stream>>>(psum, pcnt, pntrip, out);
}

// Round 2
// 23.878 us; speedup vs baseline: 3.3380x; 3.3380x over previous
//
#include <hip/hip_runtime.h>

#define NPTS 512
#define DIM 128
#define MARGIN 0.2f

// One block per anchor, 512 threads (one distance column per thread).
__global__ __launch_bounds__(512) void triplet_partial_kernel(
    const float* __restrict__ z, const int* __restrict__ labels,
    float* __restrict__ psum, unsigned* __restrict__ pcnt,
    unsigned* __restrict__ pntrip)
{
    __shared__ float za[DIM];
    __shared__ float drow[NPTS];
    __shared__ int lab[NPTS];
    __shared__ int plist[NPTS];
    __shared__ float pdm[NPTS];
    __shared__ int wcnt[8];
    __shared__ float red_f[8];
    __shared__ unsigned red_c[8];

    const int a = blockIdx.x;
    const int t = threadIdx.x;

    if (t < DIM) za[t] = z[(size_t)a * DIM + t];
    lab[t] = labels[t];
    __syncthreads();

    // Distance for column j = t: 32 independent float4 L2 loads, pipelined.
    {
        const float4* zr = reinterpret_cast<const float4*>(z + (size_t)t * DIM);
        const float4* zaf = reinterpret_cast<const float4*>(za);
        float acc = 0.f;
        #pragma unroll
        for (int k = 0; k < DIM / 4; ++k) {
            float4 v = zr[k];
            float4 w = zaf[k];          // LDS broadcast (uniform addr, free)
            float d0 = w.x - v.x;
            float d1 = w.y - v.y;
            float d2 = w.z - v.z;
            float d3 = w.w - v.w;
            acc += d0 * d0 + d1 * d1 + d2 * d2 + d3 * d3;
        }
        drow[t] = sqrtf(acc);
    }

    const int la = lab[a];

    // Deterministic compaction of positives (p: lab[p]==la, p!=a).
    const bool pred = (lab[t] == la) && (t != a);
    const unsigned long long m = __ballot(pred);
    const int wid = t >> 6;
    const int lane = t & 63;
    if (lane == 0) wcnt[wid] = __popcll(m);
    __syncthreads();            // also covers drow[] writes

    int np = 0, base = 0;
    #pragma unroll
    for (int w = 0; w < 8; ++w) {
        int c = wcnt[w];
        if (w < wid) base += c;
        np += c;
    }
    if (pred) plist[base + __popcll(m & ((1ull << lane) - 1ull))] = t;
    __syncthreads();

    if (t < np) pdm[t] = drow[plist[t]] + MARGIN;
    __syncthreads();

    // Each thread owns one negative candidate n = t.
    const bool vn = (lab[t] != la);
    const float dn = drow[t];
    float sum = 0.f;
    unsigned cnt = 0;
    for (int i = 0; i < np; ++i) {       // np ~ 8-25, uniform loop
        float v = pdm[i] - dn;           // pdm[i]: LDS broadcast
        if (v > 0.f) { sum += v; ++cnt; }
    }
    if (!vn) { sum = 0.f; cnt = 0; }

    // Reduce across 8 waves.
    #pragma unroll
    for (int off = 32; off > 0; off >>= 1) {
        sum += __shfl_down(sum, off, 64);
        cnt += __shfl_down(cnt, off, 64);
    }
    if (lane == 0) { red_f[wid] = sum; red_c[wid] = cnt; }
    __syncthreads();
    if (t == 0) {
        float S = 0.f;
        unsigned C = 0;
        #pragma unroll
        for (int w = 0; w < 8; ++w) { S += red_f[w]; C += red_c[w]; }
        psum[a] = S;
        pcnt[a] = C;
        pntrip[a] = (unsigned)np * (unsigned)(NPTS - 1 - np);
    }
}

// Single-block deterministic reduction of the 512 per-anchor partials.
__global__ __launch_bounds__(512) void triplet_final_kernel(
    const float* __restrict__ psum, const unsigned* __restrict__ pcnt,
    const unsigned* __restrict__ pntrip, float* __restrict__ out)
{
    __shared__ float rf[8];
    __shared__ unsigned rc[8], rn[8];

    const int t = threadIdx.x;
    float s = psum[t];
    unsigned c = pcnt[t];
    unsigned nt = pntrip[t];

    #pragma unroll
    for (int off = 32; off > 0; off >>= 1) {
        s  += __shfl_down(s,  off, 64);
        c  += __shfl_down(c,  off, 64);
        nt += __shfl_down(nt, off, 64);
    }
    const int wave = t >> 6;
    const int lane = t & 63;
    if (lane == 0) { rf[wave] = s; rc[wave] = c; rn[wave] = nt; }
    __syncthreads();
    if (t == 0) {
        double S = 0.0;
        unsigned C = 0, NT = 0;
        #pragma unroll
        for (int w = 0; w < 8; ++w) { S += (double)rf[w]; C += rc[w]; NT += rn[w]; }
        out[0] = (float)(S / (double)NT);
        out[1] = (float)C;
    }
}

extern "C" void kernel_launch(void* const* d_in, const int* in_sizes, int n_in,
                              void* d_out, int out_size, void* d_ws, size_t ws_size,
                              hipStream_t stream) {
    const float* z = (const float*)d_in[0];
    const int* labels = (const int*)d_in[1];
    float* out = (float*)d_out;

    float* psum = (float*)d_ws;
    unsigned* pcnt = (unsigned*)((char*)d_ws + NPTS * sizeof(float));
    unsigned* pntrip = pcnt + NPTS;

    triplet_partial_kernel<<<NPTS, 512, 0, stream>>>(z, labels, psum, pcnt, pntrip);
    triplet_final_kernel<<<1, NPTS, 0, stream>>>(psum, pcnt, pntrip, out);
}

// Round 3
// 22.478 us; speedup vs baseline: 3.5458x; 1.0623x over previous
//
#include <hip/hip_runtime.h>

#define NPTS 512
#define DIM 128
#define MARGIN 0.2f
#define ATILE 4
#define NBLK (NPTS / ATILE)   // 128 blocks

// One block per 4 anchors, 512 threads (thread t = candidate column j = t).
// Anchor rows + anchor labels are block-uniform -> scalar (SMEM) loads.
// Distances to this thread's column stay in registers; only the compacted
// positive list (d(a,p)+margin) goes through LDS, read back as float4
// broadcasts.
__global__ __launch_bounds__(512) void triplet_partial_kernel(
    const float* __restrict__ z, const int* __restrict__ labels,
    float* __restrict__ psum, unsigned* __restrict__ pcnt,
    unsigned* __restrict__ pntrip)
{
    __shared__ float pdm[ATILE][NPTS];   // d(a_i, p) + margin, compacted + padded
    __shared__ int wcnt[ATILE][8];
    __shared__ float red_f[8];
    __shared__ unsigned red_c[8];

    const int t = threadIdx.x;
    const int a0 = blockIdx.x * ATILE;
    const int wid = t >> 6;
    const int lane = t & 63;

    const int lt = labels[t];            // coalesced vector load (own label)

    int la[ATILE];
    #pragma unroll
    for (int i = 0; i < ATILE; ++i) la[i] = labels[a0 + i];   // uniform s_load

    // ---- distances s[i] = d(a0+i, t), all in registers ----
    float s[ATILE];
    {
        const float4* zr = reinterpret_cast<const float4*>(z) + (size_t)t * (DIM / 4);
        const float4* za = reinterpret_cast<const float4*>(z) + (size_t)a0 * (DIM / 4);
        float acc[ATILE] = {0.f, 0.f, 0.f, 0.f};
        #pragma unroll
        for (int k = 0; k < DIM / 4; ++k) {
            float4 v = zr[k];                        // per-lane global load
            #pragma unroll
            for (int i = 0; i < ATILE; ++i) {
                float4 w = za[i * (DIM / 4) + k];    // block-uniform -> SMEM
                float d0 = w.x - v.x;
                float d1 = w.y - v.y;
                float d2 = w.z - v.z;
                float d3 = w.w - v.w;
                acc[i] += d0 * d0 + d1 * d1 + d2 * d2 + d3 * d3;
            }
        }
        #pragma unroll
        for (int i = 0; i < ATILE; ++i) s[i] = sqrtf(acc[i]);
    }

    // ---- compact positives for each anchor (deterministic order) ----
    bool pred[ATILE];
    unsigned long long m[ATILE];
    #pragma unroll
    for (int i = 0; i < ATILE; ++i) {
        pred[i] = (lt == la[i]) && (t != a0 + i);
        m[i] = __ballot(pred[i]);
        if (lane == 0) wcnt[i][wid] = (int)__popcll(m[i]);
    }
    __syncthreads();

    unsigned np[ATILE], npad[ATILE];
    #pragma unroll
    for (int i = 0; i < ATILE; ++i) {
        unsigned base = 0, n = 0;
        #pragma unroll
        for (int w = 0; w < 8; ++w) {
            unsigned c = (unsigned)wcnt[i][w];
            if (w < wid) base += c;
            n += c;
        }
        np[i] = n;
        npad[i] = (n + 3u) & ~3u;                   // pad to float4 multiple
        if (pred[i])
            pdm[i][base + __popcll(m[i] & ((1ull << lane) - 1ull))] = s[i] + MARGIN;
        if ((unsigned)t >= n && (unsigned)t < npad[i])
            pdm[i][t] = -1e30f;                     // padding never triggers relu
    }
    __syncthreads();

    // ---- accumulate: thread t is negative n = t for each anchor ----
    float sum = 0.f;
    unsigned cnt = 0;
    #pragma unroll
    for (int i = 0; i < ATILE; ++i) {
        if (lt != la[i]) {                           // valid negative
            const float si = s[i];
            const float4* p4 = reinterpret_cast<const float4*>(pdm[i]);
            const int n4 = (int)(npad[i] >> 2);
            for (int p = 0; p < n4; ++p) {           // ~2-6 iters typical
                float4 q = p4[p];                    // LDS broadcast b128
                float v0 = q.x - si, v1 = q.y - si, v2 = q.z - si, v3 = q.w - si;
                if (v0 > 0.f) { sum += v0; ++cnt; }
                if (v1 > 0.f) { sum += v1; ++cnt; }
                if (v2 > 0.f) { sum += v2; ++cnt; }
                if (v3 > 0.f) { sum += v3; ++cnt; }
            }
        }
    }

    // ---- block reduction ----
    #pragma unroll
    for (int off = 32; off > 0; off >>= 1) {
        sum += __shfl_down(sum, off, 64);
        cnt += __shfl_down(cnt, off, 64);
    }
    if (lane == 0) { red_f[wid] = sum; red_c[wid] = cnt; }
    __syncthreads();
    if (t == 0) {
        float S = 0.f;
        unsigned C = 0;
        #pragma unroll
        for (int w = 0; w < 8; ++w) { S += red_f[w]; C += red_c[w]; }
        unsigned NT = 0;
        #pragma unroll
        for (int i = 0; i < ATILE; ++i) NT += np[i] * (unsigned)(NPTS - 1 - np[i]);
        psum[blockIdx.x] = S;
        pcnt[blockIdx.x] = C;
        pntrip[blockIdx.x] = NT;
    }
}

// Deterministic reduction of the 128 per-block partials.
__global__ __launch_bounds__(128) void triplet_final_kernel(
    const float* __restrict__ psum, const unsigned* __restrict__ pcnt,
    const unsigned* __restrict__ pntrip, float* __restrict__ out)
{
    __shared__ float rf[2];
    __shared__ unsigned rc[2], rn[2];

    const int t = threadIdx.x;
    float s = psum[t];
    unsigned c = pcnt[t];
    unsigned nt = pntrip[t];

    #pragma unroll
    for (int off = 32; off > 0; off >>= 1) {
        s  += __shfl_down(s,  off, 64);
        c  += __shfl_down(c,  off, 64);
        nt += __shfl_down(nt, off, 64);
    }
    const int wid = t >> 6;
    const int lane = t & 63;
    if (lane == 0) { rf[wid] = s; rc[wid] = c; rn[wid] = nt; }
    __syncthreads();
    if (t == 0) {
        double S = (double)rf[0] + (double)rf[1];
        unsigned C = rc[0] + rc[1];
        unsigned NT = rn[0] + rn[1];
        out[0] = (float)(S / (double)NT);
        out[1] = (float)C;
    }
}

extern "C" void kernel_launch(void* const* d_in, const int* in_sizes, int n_in,
                              void* d_out, int out_size, void* d_ws, size_t ws_size,
                              hipStream_t stream) {
    const float* z = (const float*)d_in[0];
    const int* labels = (const int*)d_in[1];
    float* out = (float*)d_out;

    float* psum = (float*)d_ws;
    unsigned* pcnt = (unsigned*)((char*)d_ws + NBLK * sizeof(float));
    unsigned* pntrip = pcnt + NBLK;

    triplet_partial_kernel<<<NBLK, 512, 0, stream>>>(z, labels, psum, pcnt, pntrip);
    triplet_final_kernel<<<1, NBLK, 0, stream>>>(psum, pcnt, pntrip, out);
}

// Round 4
// 15.429 us; speedup vs baseline: 5.1658x; 1.4569x over previous
//
#include <hip/hip_runtime.h>

#define NPTS 512
#define DIM 128
#define MARGIN 0.2f
#define ATILE 2
#define NBLK (NPTS / ATILE)     // 256 blocks
#define TROWS 128               // rows per LDS stage tile
#define NTILE (NPTS / TROWS)    // 4 tiles

// One block per 2 anchors, 512 threads. z staged through LDS in coalesced,
// XOR-swizzled 64KB tiles; distances computed from LDS (k split 4-way).
__global__ __launch_bounds__(512) void triplet_partial_kernel(
    const float* __restrict__ z, const int* __restrict__ labels,
    float* __restrict__ psum, unsigned* __restrict__ pcnt,
    unsigned* __restrict__ pntrip)
{
    __shared__ float4 stage[TROWS * 32];                 // 64 KB
    __shared__ float part[4][TROWS][ATILE];              // 4 KB
    __shared__ float drow[ATILE][NPTS];                  // 4 KB
    __shared__ __align__(16) float pdm[ATILE][NPTS];     // 4 KB
    __shared__ int wcnt[ATILE][8];
    __shared__ float red_f[8];
    __shared__ unsigned red_c[8];

    const int t = threadIdx.x;
    const int a0 = blockIdx.x * ATILE;
    const int wid = t >> 6, lane = t & 63;
    const int q = t >> 7;               // k-quarter (uniform per wave)
    const int r = t & (TROWS - 1);      // row within tile

    const float4* zg = reinterpret_cast<const float4*>(z);

    // Anchor rows (own k-quarter) in registers; lane-uniform addr -> 1 txn each.
    float4 za[ATILE][8];
    #pragma unroll
    for (int i = 0; i < ATILE; ++i)
        #pragma unroll
        for (int kk = 0; kk < 8; ++kk)
            za[i][kk] = zg[(size_t)(a0 + i) * 32 + q * 8 + kk];

    // ---- distance phase: 4 staged tiles ----
    for (int T = 0; T < NTILE; ++T) {
        #pragma unroll
        for (int p = 0; p < 8; ++p) {                    // coalesced stage
            int f = p * 512 + t;                         // 0..4095
            int row = f >> 5, chunk = f & 31;
            stage[row * 32 + (chunk ^ (row & 7))] =
                zg[(size_t)(T * TROWS + row) * 32 + chunk];
        }
        __syncthreads();                                 // stage ready; prev part reads done

        float acc0 = 0.f, acc1 = 0.f;
        const int rx = r & 7;
        #pragma unroll
        for (int kk = 0; kk < 8; ++kk) {
            float4 v = stage[r * 32 + ((q * 8 + kk) ^ rx)];
            float4 w0 = za[0][kk], w1 = za[1][kk];
            float d0 = w0.x - v.x, d1 = w0.y - v.y, d2 = w0.z - v.z, d3 = w0.w - v.w;
            acc0 += d0 * d0 + d1 * d1 + d2 * d2 + d3 * d3;
            float e0 = w1.x - v.x, e1 = w1.y - v.y, e2 = w1.z - v.z, e3 = w1.w - v.w;
            acc1 += e0 * e0 + e1 * e1 + e2 * e2 + e3 * e3;
        }
        part[q][r][0] = acc0;
        part[q][r][1] = acc1;
        __syncthreads();                                 // part ready; stage reads done

        if (t < TROWS) {
            float s0 = part[0][t][0] + part[1][t][0] + part[2][t][0] + part[3][t][0];
            float s1 = part[0][t][1] + part[1][t][1] + part[2][t][1] + part[3][t][1];
            drow[0][T * TROWS + t] = sqrtf(s0);
            drow[1][T * TROWS + t] = sqrtf(s1);
        }
        // next iteration's first __syncthreads orders drow/part reads vs rewrites
    }
    __syncthreads();                                     // drow complete

    // ---- compact positives per anchor (deterministic order) ----
    const int lt = labels[t];
    int la[ATILE];
    #pragma unroll
    for (int i = 0; i < ATILE; ++i) la[i] = labels[a0 + i];

    bool pred[ATILE];
    unsigned long long m[ATILE];
    #pragma unroll
    for (int i = 0; i < ATILE; ++i) {
        pred[i] = (lt == la[i]) && (t != a0 + i);
        m[i] = __ballot(pred[i]);
        if (lane == 0) wcnt[i][wid] = (int)__popcll(m[i]);
    }
    __syncthreads();

    unsigned np[ATILE], npad[ATILE];
    #pragma unroll
    for (int i = 0; i < ATILE; ++i) {
        unsigned base = 0, n = 0;
        #pragma unroll
        for (int w = 0; w < 8; ++w) {
            unsigned c = (unsigned)wcnt[i][w];
            if (w < wid) base += c;
            n += c;
        }
        np[i] = n;
        npad[i] = (n + 3u) & ~3u;
        if (pred[i])
            pdm[i][base + __popcll(m[i] & ((1ull << lane) - 1ull))] = drow[i][t] + MARGIN;
        if ((unsigned)t >= n && (unsigned)t < npad[i])
            pdm[i][t] = -1e30f;                          // padding never fires relu
    }
    __syncthreads();

    // ---- accumulate: thread t = negative candidate t ----
    float sum = 0.f;
    unsigned cnt = 0;
    #pragma unroll
    for (int i = 0; i < ATILE; ++i) {
        if (lt != la[i]) {
            const float si = drow[i][t];
            const float4* p4 = reinterpret_cast<const float4*>(pdm[i]);
            const int n4 = (int)(npad[i] >> 2);
            for (int p = 0; p < n4; ++p) {
                float4 qv = p4[p];                       // LDS broadcast
                float v0 = qv.x - si, v1 = qv.y - si, v2 = qv.z - si, v3 = qv.w - si;
                if (v0 > 0.f) { sum += v0; ++cnt; }
                if (v1 > 0.f) { sum += v1; ++cnt; }
                if (v2 > 0.f) { sum += v2; ++cnt; }
                if (v3 > 0.f) { sum += v3; ++cnt; }
            }
        }
    }

    // ---- block reduction ----
    #pragma unroll
    for (int off = 32; off > 0; off >>= 1) {
        sum += __shfl_down(sum, off, 64);
        cnt += __shfl_down(cnt, off, 64);
    }
    if (lane == 0) { red_f[wid] = sum; red_c[wid] = cnt; }
    __syncthreads();
    if (t == 0) {
        float S = 0.f;
        unsigned C = 0;
        #pragma unroll
        for (int w = 0; w < 8; ++w) { S += red_f[w]; C += red_c[w]; }
        unsigned NT = 0;
        #pragma unroll
        for (int i = 0; i < ATILE; ++i) NT += np[i] * (unsigned)(NPTS - 1 - np[i]);
        psum[blockIdx.x] = S;
        pcnt[blockIdx.x] = C;
        pntrip[blockIdx.x] = NT;
    }
}

// Deterministic reduction of the 256 per-block partials.
__global__ __launch_bounds__(256) void triplet_final_kernel(
    const float* __restrict__ psum, const unsigned* __restrict__ pcnt,
    const unsigned* __restrict__ pntrip, float* __restrict__ out)
{
    __shared__ float rf[4];
    __shared__ unsigned rc[4], rn[4];

    const int t = threadIdx.x;
    float s = psum[t];
    unsigned c = pcnt[t];
    unsigned nt = pntrip[t];

    #pragma unroll
    for (int off = 32; off > 0; off >>= 1) {
        s  += __shfl_down(s,  off, 64);
        c  += __shfl_down(c,  off, 64);
        nt += __shfl_down(nt, off, 64);
    }
    const int wid = t >> 6, lane = t & 63;
    if (lane == 0) { rf[wid] = s; rc[wid] = c; rn[wid] = nt; }
    __syncthreads();
    if (t == 0) {
        double S = 0.0;
        unsigned C = 0, NT = 0;
        #pragma unroll
        for (int w = 0; w < 4; ++w) { S += (double)rf[w]; C += rc[w]; NT += rn[w]; }
        out[0] = (float)(S / (double)NT);
        out[1] = (float)C;
    }
}

extern "C" void kernel_launch(void* const* d_in, const int* in_sizes, int n_in,
                              void* d_out, int out_size, void* d_ws, size_t ws_size,
                              hipStream_t stream) {
    const float* z = (const float*)d_in[0];
    const int* labels = (const int*)d_in[1];
    float* out = (float*)d_out;

    float* psum = (float*)d_ws;
    unsigned* pcnt = (unsigned*)((char*)d_ws + NBLK * sizeof(float));
    unsigned* pntrip = pcnt + NBLK;

    triplet_partial_kernel<<<NBLK, 512, 0, stream>>>(z, labels, psum, pcnt, pntrip);
    triplet_final_kernel<<<1, NBLK, 0, stream>>>(psum, pcnt, pntrip, out);
}